// Round 1
// baseline (319.595 us; speedup 1.0000x reference)
//
#include <hip/hip_runtime.h>

// B=8, N=32, T=64, D=128, E=4, H=32, BT=512
// R10: split the fused kernel into GEMM (k1_proj) + attention epilogue (k2_attn).
// Rationale (rocprof): old gnn_fused FETCH=236MB/dispatch = 1024 blocks x 160KB
// weight re-stream with MFMA operands fed straight from global -> latency-bound
// (MfmaUtil 0.7%, VALUBusy 6.6%). k1 stages all projection weights ONCE per block
// in 114KB LDS (28x reuse per wave); k2 has no weight streaming except a 32KB
// L2-resident Theta prefetch. Numerics bit-identical to R9 path.
// Fallback to the R9 kernels if ws_size < 23.3MB.

typedef __bf16 bf16x8 __attribute__((ext_vector_type(8)));
typedef float  f32x4  __attribute__((ext_vector_type(4)));

static __device__ __forceinline__ unsigned short f2bf(float f) {
    unsigned u = __float_as_uint(f);
    u += 0x7fffu + ((u >> 16) & 1u);        // RNE
    return (unsigned short)(u >> 16);
}
static __device__ __forceinline__ float bf2f(unsigned short u) {
    return __uint_as_float(((unsigned)u) << 16);
}
static __device__ __forceinline__ unsigned pack2(float a, float b) {
    return (unsigned)f2bf(a) | ((unsigned)f2bf(b) << 16);
}

// ---------------------------------------------------------------------------
// Wfrag (16B chunks): [0,2048) Wq | [2048,4096) Wk | [4096,6144) Wv |
// [6144,8192) Theta | chunk 8192+: Cq=W1q@Wq (512), chunk 8704+: Ck=W1k@Wk (512).
// B-frag chunk (nt*4+ks)*64+lane holds B[k=j][n]: n = nt*16+(lane&15),
// j = ks*32+(lane>>4)*8 + (0..7).
// ---------------------------------------------------------------------------

// ===== NEW: merged pack + compose prep (replaces k0a+k0b on the fast path) ===
__global__ __launch_bounds__(256) void k0_prep(
    const float* __restrict__ Wq, const float* __restrict__ Wk,
    const float* __restrict__ Wv, const float* __restrict__ Theta,
    const float* __restrict__ W1, unsigned short* __restrict__ Wfrag)
{
    const int tid = threadIdx.x;
    if (blockIdx.x < 32) {
        // pack Wq/Wk/Wv/Theta to bf16 B-frags (identical to k0a)
        int gid = blockIdx.x * 256 + tid;      // 0..8191
        int g = gid >> 11, c = gid & 2047;
        int ntk = c >> 6, lane = c & 63;
        int i = (ntk >> 2) * 16 + (lane & 15);
        int j = (ntk & 3) * 32 + (lane >> 4) * 8;
        const float* src = (g == 0 ? Wq : g == 1 ? Wk : g == 2 ? Wv : Theta) + (size_t)i * 128 + j;
        float4 a = *(const float4*)(src);
        float4 b = *(const float4*)(src + 4);
        uint4 pk;
        pk.x = pack2(a.x, a.y); pk.y = pack2(a.z, a.w);
        pk.z = pack2(b.x, b.y); pk.w = pack2(b.z, b.w);
        *(uint4*)(Wfrag + (size_t)gid * 8) = pk;
    } else {
        // compose Cq = W1q@Wq, Ck = W1k@Wk (identical math/order to k0b)
        int b2 = blockIdx.x - 32;              // 0..31
        int mat = b2 & 1;
        int hbase = (b2 >> 1) * 2;
        int hl = tid >> 7, col = tid & 127;
        int h = hbase + hl;
        const float* Wsel = mat ? Wk : Wq;
        const float* w1r = W1 + (size_t)h * 260 + mat * 128;
        float acc = 0.f;
        for (int i = 0; i < 128; ++i)
            acc = fmaf(w1r[i], Wsel[(size_t)i * 128 + col], acc);
        int nt = h >> 4;
        unsigned base = 65536u + (unsigned)mat * 4096u;   // shorts
        int lane = (h & 15) | (((col >> 3) & 3) << 4);
        int ks = col >> 5, vj = col & 7;
        Wfrag[base + (unsigned)((nt * 4 + ks) * 64 + lane) * 8 + vj] = f2bf(acc);
    }
}

// ===== NEW: projection GEMM. M=16384 tokens, N=448 (Q|K|V|hq|hk), K=128 ======
// grid 256 x 256 threads, 1 block/CU (128KB LDS). Each wave handles the nt set
// {wv, wv+4, ..., wv+24} for ALL 4 token groups (B-frag LDS reads amortized 4x).
__global__ __launch_bounds__(256, 1)
void k1_proj(const float* __restrict__ x,
             const unsigned short* __restrict__ Wfrag,
             const float* __restrict__ b1,
             float* __restrict__ Qws, float* __restrict__ Kws,
             unsigned short* __restrict__ Vws,
             unsigned short* __restrict__ hqws, unsigned short* __restrict__ hkws)
{
    __shared__ __align__(16) unsigned short Wlds[7168 * 8];  // 114688 B
    __shared__ __align__(16) unsigned short Zf[1024 * 8];    // 16384 B
    const int tid = threadIdx.x;
    const int Mbase = blockIdx.x * 64;

    // stage weights: LDS chunks [0,6144) <- global [0,6144)  (Wq|Wk|Wv)
    //                LDS chunks [6144,7168) <- global [8192,9216) (Cq|Ck)
    {
        const uint4* src = (const uint4*)Wfrag;
        uint4* dst = (uint4*)Wlds;
#pragma unroll
        for (int i = 0; i < 24; ++i) dst[tid + 256 * i] = src[tid + 256 * i];
#pragma unroll
        for (int i = 0; i < 4; ++i) dst[6144 + tid + 256 * i] = src[8192 + tid + 256 * i];
    }
    // stage Z bf16 A-frags for 64 tokens (identical packing to R9 P0)
#pragma unroll
    for (int it = 0; it < 4; ++it) {
        int f = tid + 256 * it;                 // chunk 0..1023
        int lane9 = f & 63, tk = f >> 6;
        int nl = (tk >> 2) * 16 + (lane9 & 15); // token-local 0..63
        int d  = (tk & 3) * 32 + (lane9 >> 4) * 8;
        int tok = Mbase + nl;
        int n = tok & 31, bt = tok >> 5;
        int b_ = bt >> 6, t_ = bt & 63;
        const float* xr = x + ((size_t)((b_ * 32 + n) * 64 + t_)) * 128 + d;
        float4 a = *(const float4*)(xr);
        float4 b = *(const float4*)(xr + 4);
        uint4 pk;
        pk.x = pack2(a.x, a.y); pk.y = pack2(a.z, a.w);
        pk.z = pack2(b.x, b.y); pk.w = pack2(b.z, b.w);
        *(uint4*)(Zf + f * 8) = pk;
    }
    __syncthreads();

    const int wv = tid >> 6, lane = tid & 63;
    const int quad = lane >> 4, col0 = lane & 15;
    const float b1lo = b1[col0], b1hi = b1[16 + col0];
    const bf16x8* WL = (const bf16x8*)Wlds;

    bf16x8 avZ[4][4];   // [token-group][ks]
#pragma unroll
    for (int tg = 0; tg < 4; ++tg)
#pragma unroll
        for (int ks = 0; ks < 4; ++ks)
            avZ[tg][ks] = *(const bf16x8*)(Zf + ((tg * 4 + ks) * 64 + lane) * 8);

    const f32x4 zero = {0.f, 0.f, 0.f, 0.f};
#pragma unroll
    for (int k7 = 0; k7 < 7; ++k7) {
        const int nt = wv + k7 * 4;             // wave-uniform
        const int cbase = (nt < 24) ? nt * 256 : 6144 + (nt - 24) * 256;
        f32x4 acc[4] = {zero, zero, zero, zero};
#pragma unroll
        for (int ks = 0; ks < 4; ++ks) {
            bf16x8 bw = WL[cbase + ks * 64 + lane];
#pragma unroll
            for (int tg = 0; tg < 4; ++tg)
                acc[tg] = __builtin_amdgcn_mfma_f32_16x16x32_bf16(avZ[tg][ks], bw, acc[tg], 0, 0, 0);
        }
#pragma unroll
        for (int tg = 0; tg < 4; ++tg) {
            int tokb = Mbase + tg * 16 + quad * 4;
#pragma unroll
            for (int reg = 0; reg < 4; ++reg) {
                size_t tok = (size_t)(tokb + reg);
                float v = acc[tg][reg];
                if (nt < 8)       Qws[tok * 128 + nt * 16 + col0] = v;
                else if (nt < 16) Kws[tok * 128 + (nt - 8) * 16 + col0] = v;
                else if (nt < 24) Vws[tok * 128 + (nt - 16) * 16 + col0] = f2bf(v);
                else if (nt < 26) hqws[tok * 32 + (nt - 24) * 16 + col0] = f2bf(v + (nt == 24 ? b1lo : b1hi));
                else              hkws[tok * 32 + (nt - 26) * 16 + col0] = f2bf(v);
            }
        }
    }
}

// ===== NEW: per-bt attention epilogue. grid 512 x 256, 3 blocks/CU ==========
#define LD16W(dst, ptr) { const uint4* _p = (const uint4*)(ptr);               \
    uint4 _a = _p[0], _b = _p[1], _c = _p[2], _d = _p[3];                      \
    dst[0]=_a.x; dst[1]=_a.y; dst[2]=_a.z; dst[3]=_a.w;                        \
    dst[4]=_b.x; dst[5]=_b.y; dst[6]=_b.z; dst[7]=_b.w;                        \
    dst[8]=_c.x; dst[9]=_c.y; dst[10]=_c.z; dst[11]=_c.w;                      \
    dst[12]=_d.x; dst[13]=_d.y; dst[14]=_d.z; dst[15]=_d.w; }

__global__ __launch_bounds__(256, 3)
void k2_attn(const float* __restrict__ x, const float* __restrict__ edge,
             const float* __restrict__ A_prior, const unsigned char* __restrict__ pad_mask,
             const unsigned short* __restrict__ Wfrag, const float* __restrict__ Wfuse,
             const float* __restrict__ W1, const float* __restrict__ W2,
             const float* __restrict__ b2, const float* __restrict__ gma,
             const float* __restrict__ bta, const float* __restrict__ physw,
             const float* __restrict__ priorw,
             const float* __restrict__ Qws, const float* __restrict__ Kws,
             const unsigned short* __restrict__ Vws,
             const unsigned short* __restrict__ hqws, const unsigned short* __restrict__ hkws,
             float* __restrict__ out)
{
    __shared__ __align__(16) unsigned char arena[47392];
    float* Qs = (float*)arena;                               // [32][132] fp32
    float* Ks = (float*)(arena + 16896);                     // [32][132] fp32
    unsigned short* Sfrag = (unsigned short*)(arena + 16896); // alias Ks (P6+)
    unsigned short* Vs = (unsigned short*)(arena + 33792);   // [32][128] bf16
    float* Lg = (float*)(arena + 41984);                     // [32][36]
    float4* W1e_s  = (float4*)(arena + 46592);
    float*  W2_s   = (float*)(arena + 47104);
    float*  maskrow= (float*)(arena + 47232);
    float*  Wf_s   = (float*)(arena + 47360);
    float*  ThOut  = Qs;                                     // alias Qs (P7+), stride 132

    const int tid = threadIdx.x;
    const int bt  = blockIdx.x;
    const int b_ = bt >> 6, t_ = bt & 63;
    const float pw  = physw[0];
    const float rw_ = priorw[0];
    const float b2v = b2[0];

    // ---- P0: stage Q,K (fp32) / V (bf16) tiles into LDS; small weights ----
    {
        const int row = tid >> 3, cl = (tid & 7) * 4;
        const size_t gb = ((size_t)bt * 32 + row) * 128;
#pragma unroll
        for (int c = 0; c < 4; ++c) {
            int off = cl + c * 32;
            *(float4*)(Qs + row * 132 + off) = *(const float4*)(Qws + gb + off);
            *(float4*)(Ks + row * 132 + off) = *(const float4*)(Kws + gb + off);
        }
        const int vl = (tid & 7) * 8;
#pragma unroll
        for (int c = 0; c < 2; ++c) {
            int off = vl + c * 64;
            *(uint4*)(Vs + row * 128 + off) = *(const uint4*)(Vws + gb + off);
        }
    }
    if (tid < 32) {
        int h = tid;
        W1e_s[h] = *(const float4*)(W1 + (size_t)h * 260 + 256);
        W2_s[h]  = W2[h];
        maskrow[h] = pad_mask[b_ * 32 + h] ? 1.f : 0.f;
        if (h < 5) Wf_s[h] = Wfuse[h];
    }
    __syncthreads();

    // ---- P3: logits = QK^T/sqrt(d) (fp32 VALU) + pw*phys + rw*log(prior) ----
    // thread covers (n in {2*npg, 2*npg+1}) x (m in {mp, mp+16})
    {
        const int mp = tid & 15, npg = tid >> 4;
        const int n0 = npg * 2, mA = mp, mB = mp + 16;

        // issue all global prefetches up-front (consumed after the j-loop)
        unsigned hq0w[16], hq1w[16], hkAw[16], hkBw[16];
        LD16W(hq0w, hqws + ((size_t)bt * 32 + n0) * 32);
        LD16W(hq1w, hqws + ((size_t)bt * 32 + n0 + 1) * 32);
        LD16W(hkAw, hkws + ((size_t)bt * 32 + mA) * 32);
        LD16W(hkBw, hkws + ((size_t)bt * 32 + mB) * 32);
        float4 e4[2][2];
        float pr5[2][2][5];
#pragma unroll
        for (int r = 0; r < 2; ++r)
#pragma unroll
            for (int c = 0; c < 2; ++c) {
                int m = c ? mB : mA;
                e4[r][c] = *(const float4*)(edge + (((size_t)bt * 32 + (n0 + r)) * 32 + m) * 4);
                size_t pb = (((size_t)bt * 32 + (n0 + r)) * 32 + m) * 5;
#pragma unroll
                for (int j5 = 0; j5 < 5; ++j5) pr5[r][c][j5] = A_prior[pb + j5];
            }

        const float* qa = Qs + n0 * 132;
        const float* qb = qa + 132;
        const float* ka = Ks + mA * 132;
        const float* kb = Ks + mB * 132;
        float a00 = 0.f, a01 = 0.f, a10 = 0.f, a11 = 0.f;
        for (int j = 0; j < 128; j += 4) {
            float4 kva = *(const float4*)(ka + j);
            float4 kvb = *(const float4*)(kb + j);
            float4 qva = *(const float4*)(qa + j);
            float4 qvb = *(const float4*)(qb + j);
            a00 = fmaf(qva.x, kva.x, fmaf(qva.y, kva.y, fmaf(qva.z, kva.z, fmaf(qva.w, kva.w, a00))));
            a01 = fmaf(qva.x, kvb.x, fmaf(qva.y, kvb.y, fmaf(qva.z, kvb.z, fmaf(qva.w, kvb.w, a01))));
            a10 = fmaf(qvb.x, kva.x, fmaf(qvb.y, kva.y, fmaf(qvb.z, kva.z, fmaf(qvb.w, kva.w, a10))));
            a11 = fmaf(qvb.x, kvb.x, fmaf(qvb.y, kvb.y, fmaf(qvb.z, kvb.z, fmaf(qvb.w, kvb.w, a11))));
        }
        float pacc[2][2] = {{0.f, 0.f}, {0.f, 0.f}};
#pragma unroll
        for (int h = 0; h < 32; ++h) {
            float4 we = W1e_s[h];
            float w2v = W2_s[h];
            unsigned wq0 = hq0w[h >> 1], wq1 = hq1w[h >> 1];
            unsigned wkA = hkAw[h >> 1], wkB = hkBw[h >> 1];
            float hq0 = bf2f((unsigned short)((h & 1) ? (wq0 >> 16) : (wq0 & 0xffffu)));
            float hq1 = bf2f((unsigned short)((h & 1) ? (wq1 >> 16) : (wq1 & 0xffffu)));
            float hkA = bf2f((unsigned short)((h & 1) ? (wkA >> 16) : (wkA & 0xffffu)));
            float hkB = bf2f((unsigned short)((h & 1) ? (wkB >> 16) : (wkB & 0xffffu)));
#pragma unroll
            for (int r = 0; r < 2; ++r) {
                float hqv = r ? hq1 : hq0;
#pragma unroll
                for (int c = 0; c < 2; ++c) {
                    float hkv = c ? hkB : hkA;
                    float4 e = e4[r][c];
                    float he = fmaf(e.x, we.x, fmaf(e.y, we.y, fmaf(e.z, we.z, e.w * we.w)));
                    pacc[r][c] = fmaf(fmaxf(hqv + hkv + he, 0.f), w2v, pacc[r][c]);
                }
            }
        }
        float cont[2][2] = {{a00, a01}, {a10, a11}};
#pragma unroll
        for (int r = 0; r < 2; ++r)
#pragma unroll
            for (int c = 0; c < 2; ++c) {
                int n = n0 + r, m = c ? mB : mA;
                float pr = pr5[r][c][0]*Wf_s[0] + pr5[r][c][1]*Wf_s[1] + pr5[r][c][2]*Wf_s[2]
                         + pr5[r][c][3]*Wf_s[3] + pr5[r][c][4]*Wf_s[4];
                if (!(fabsf(pr) < 1e30f)) pr = 0.f;
                pr = fmaxf(pr, 0.f);
                float lg = cont[r][c] * 0.08838834764831845f
                         + pw * (pacc[r][c] + b2v) + rw_ * __logf(pr + 1e-6f);
                if (maskrow[n] != 0.f || maskrow[m] != 0.f) lg = -1e9f;
                Lg[n * 36 + m] = lg;
            }
    }
    __syncthreads();

    // ---- P4: softmax (32 rows) ----
    if (tid < 32) {
        const int n = tid;
        float mx = -3.4e38f;
        for (int m2 = 0; m2 < 32; ++m2) mx = fmaxf(mx, Lg[n * 36 + m2]);
        float s = 0.f;
        for (int m2 = 0; m2 < 32; ++m2) {
            float e = __expf(Lg[n * 36 + m2] - mx);
            Lg[n * 36 + m2] = e; s += e;
        }
        float inv = 1.f / s;
        for (int m2 = 0; m2 < 32; ++m2) Lg[n * 36 + m2] *= inv;
    }
    __syncthreads();

    const int wv = tid >> 6, lane = tid & 63;
    const int quad = lane >> 4, col0 = lane & 15;
    const int rg = wv & 1, ch = wv >> 1;

    // ---- P6: Theta-frag prefetch (global, L2-resident) + spatial = alpha @ V
    bf16x8 thf[16];
    {
        const bf16x8* Wf = (const bf16x8*)Wfrag;
#pragma unroll
        for (int nt = 0; nt < 4; ++nt)
#pragma unroll
            for (int ks = 0; ks < 4; ++ks)
                thf[nt * 4 + ks] = Wf[6144 + (((ch * 4 + nt) * 4 + ks) * 64) + lane];
    }
    {
        const int d0 = (tid & 31) * 4, ng = tid >> 5;   // 4 rows/thread: ng*4+r
        const int vks = d0 >> 5, vq = (d0 >> 3) & 3, vj = d0 & 7;
        float sa[4][4] = {};
        for (int m = 0; m < 32; m += 4) {
            float alv[4][4];
#pragma unroll
            for (int r = 0; r < 4; ++r) {
                float4 t = *(const float4*)(Lg + (ng * 4 + r) * 36 + m);
                alv[r][0] = t.x; alv[r][1] = t.y; alv[r][2] = t.z; alv[r][3] = t.w;
            }
#pragma unroll
            for (int mm = 0; mm < 4; ++mm) {
                const unsigned short* vp = Vs + (m + mm) * 128 + d0;
                float v0 = bf2f(vp[0]), v1 = bf2f(vp[1]), v2 = bf2f(vp[2]), v3 = bf2f(vp[3]);
#pragma unroll
                for (int r = 0; r < 4; ++r) {
                    float a = alv[r][mm];
                    sa[r][0] = fmaf(a, v0, sa[r][0]); sa[r][1] = fmaf(a, v1, sa[r][1]);
                    sa[r][2] = fmaf(a, v2, sa[r][2]); sa[r][3] = fmaf(a, v3, sa[r][3]);
                }
            }
        }
        // Sfrag aliases Ks (dead after P3); all threads are past the P4 barrier.
#pragma unroll
        for (int r = 0; r < 4; ++r) {
            int nloc = ng * 4 + r;
            int tg = nloc >> 4, nl = nloc & 15;
            unsigned short* sp = Sfrag + ((tg * 4 + vks) * 64 + vq * 16 + nl) * 8 + vj;
            sp[0] = f2bf(sa[r][0]); sp[1] = f2bf(sa[r][1]);
            sp[2] = f2bf(sa[r][2]); sp[3] = f2bf(sa[r][3]);
        }
    }
    __syncthreads();

    // ---- P7: Theta MFMA -> ThOut (alias Qs, stride 132) ----
    {
        const f32x4 zero = {0.f, 0.f, 0.f, 0.f};
        f32x4 aT[4] = {zero, zero, zero, zero};
#pragma unroll
        for (int ks = 0; ks < 4; ++ks) {
            bf16x8 av = *(const bf16x8*)(Sfrag + ((rg * 4 + ks) * 64 + lane) * 8);
#pragma unroll
            for (int nt = 0; nt < 4; ++nt)
                aT[nt] = __builtin_amdgcn_mfma_f32_16x16x32_bf16(av, thf[nt * 4 + ks], aT[nt], 0, 0, 0);
        }
#pragma unroll
        for (int nt = 0; nt < 4; ++nt) {
            int colc = ch * 64 + nt * 16 + col0;
#pragma unroll
            for (int reg = 0; reg < 4; ++reg)
                ThOut[(rg * 16 + quad * 4 + reg) * 132 + colc] = aT[nt][reg];
        }
    }
    __syncthreads();

    // ---- P8: y = x + ThOut; LayerNorm; mask; store (4 rows/thread) ----
    {
        const int d0 = (tid & 31) * 4, ng = tid >> 5;
        float4 g4  = *(const float4*)(gma + d0);
        float4 be4 = *(const float4*)(bta + d0);
#pragma unroll
        for (int r = 0; r < 4; ++r) {
            int nloc = ng * 4 + r;
            const float* xr = x + ((size_t)((b_ * 32 + nloc) * 64 + t_)) * 128 + d0;
            float4 z  = *(const float4*)(xr);
            float4 th = *(const float4*)(ThOut + nloc * 132 + d0);
            float y0 = th.x + z.x, y1 = th.y + z.y, y2 = th.z + z.z, y3 = th.w + z.w;
            float s  = (y0 + y1) + (y2 + y3);
            float s2 = (y0*y0 + y1*y1) + (y2*y2 + y3*y3);
#pragma unroll
            for (int off = 1; off < 32; off <<= 1) {
                s  += __shfl_xor(s,  off, 64);
                s2 += __shfl_xor(s2, off, 64);
            }
            float mu   = s * 0.0078125f;
            float var  = s2 * 0.0078125f - mu * mu;
            float rstd = rsqrtf(var + 1e-5f);
            float msk  = (maskrow[nloc] != 0.f) ? 0.f : 1.f;
            float4 o;
            o.x = ((y0 - mu) * rstd * g4.x + be4.x) * msk;
            o.y = ((y1 - mu) * rstd * g4.y + be4.y) * msk;
            o.z = ((y2 - mu) * rstd * g4.z + be4.z) * msk;
            o.w = ((y3 - mu) * rstd * g4.w + be4.w) * msk;
            *(float4*)(out + ((size_t)((b_ * 32 + nloc) * 64 + t_)) * 128 + d0) = o;
        }
    }
}

// ===========================================================================
// ===== R9 FALLBACK PATH (used only if ws_size is too small) ================
// ===========================================================================
__global__ __launch_bounds__(256) void k0a_pack_w(
    const float* __restrict__ Wq, const float* __restrict__ Wk,
    const float* __restrict__ Wv, const float* __restrict__ Theta,
    unsigned short* __restrict__ Wfrag)
{
    int gid = blockIdx.x * 256 + threadIdx.x;      // 0..8191
    int g = gid >> 11, c = gid & 2047;
    int ntk = c >> 6, lane = c & 63;
    int i = (ntk >> 2) * 16 + (lane & 15);
    int j = (ntk & 3) * 32 + (lane >> 4) * 8;
    const float* src = (g == 0 ? Wq : g == 1 ? Wk : g == 2 ? Wv : Theta) + (size_t)i * 128 + j;
    float4 a = *(const float4*)(src);
    float4 b = *(const float4*)(src + 4);
    uint4 pk;
    pk.x = pack2(a.x, a.y); pk.y = pack2(a.z, a.w);
    pk.z = pack2(b.x, b.y); pk.w = pack2(b.z, b.w);
    *(uint4*)(Wfrag + (size_t)gid * 8) = pk;
}

__global__ __launch_bounds__(256, 1) void k0b_compose(
    const float* __restrict__ Wq, const float* __restrict__ Wk,
    const float* __restrict__ W1, unsigned short* __restrict__ Wfrag)
{
    __shared__ __align__(16) float Ws[128 * 132];
    __shared__ __align__(16) float W1s[8 * 128];
    const int tid = threadIdx.x;
    const int mat   = blockIdx.x & 1;
    const int hbase = (blockIdx.x >> 1) * 8;
    const float* Wsel = mat ? Wk : Wq;
#pragma unroll
    for (int q = 0; q < 16; ++q) {
        int f = tid + 256 * q;
        int i = f >> 5, c4 = (f & 31) * 4;
        *(float4*)(Ws + i * 132 + c4) = *(const float4*)(Wsel + (size_t)i * 128 + c4);
    }
#pragma unroll
    for (int q = 0; q < 4; ++q) {
        int f = tid + 256 * q;
        int hl = f >> 7, i = f & 127;
        W1s[hl * 128 + i] = W1[(size_t)(hbase + hl) * 260 + mat * 128 + i];
    }
    __syncthreads();
    const int hl = tid >> 5;
    const int h  = hbase + hl;
    const int j0 = (tid & 31) * 4;
    float4 acc = {0.f, 0.f, 0.f, 0.f};
    for (int i = 0; i < 128; ++i) {
        float c = W1s[hl * 128 + i];
        float4 w = *(const float4*)(Ws + i * 132 + j0);
        acc.x = fmaf(c, w.x, acc.x); acc.y = fmaf(c, w.y, acc.y);
        acc.z = fmaf(c, w.z, acc.z); acc.w = fmaf(c, w.w, acc.w);
    }
    const int nt = h >> 4;
    const unsigned base = 65536u + (unsigned)mat * 4096u;   // shorts
    float av[4] = {acc.x, acc.y, acc.z, acc.w};
#pragma unroll
    for (int jj = 0; jj < 4; ++jj) {
        int j = j0 + jj;
        int lane = (h & 15) | (((j >> 3) & 3) << 4);
        int ks = j >> 5, vj = j & 7;
        Wfrag[base + (unsigned)((nt * 4 + ks) * 64 + lane) * 8 + vj] = f2bf(av[jj]);
    }
}

__global__ __launch_bounds__(256, 4)
void gnn_fused(const float* __restrict__ x,
               const float* __restrict__ edge,
               const float* __restrict__ A_prior,
               const unsigned char* __restrict__ pad_mask,
               const unsigned short* __restrict__ Wfrag,
               const float* __restrict__ Wfuse,
               const float* __restrict__ W1,
               const float* __restrict__ b1,
               const float* __restrict__ W2,
               const float* __restrict__ b2,
               const float* __restrict__ gma,
               const float* __restrict__ bta,
               const float* __restrict__ physw,
               const float* __restrict__ priorw,
               float* __restrict__ out)
{
    __shared__ __align__(16) unsigned char arena[39648];
    unsigned short* Zfrag = (unsigned short*)(arena);
    float*          Qs    = (float*)(arena);
    unsigned short* Sfrag = (unsigned short*)(arena);
    float*          Ks    = (float*)(arena + 8192);
    unsigned short* Vfrag = (unsigned short*)(arena + 25088);
    float*          ThOut = (float*)(arena + 25088);
    float*          Lg    = (float*)(arena + 33280);
    unsigned short* hqT   = (unsigned short*)(arena + 35392);
    unsigned short* hks   = (unsigned short*)(arena + 36544);
    float4* W1e_s  = (float4*)(arena + 38720);
    float*  W2_s   = (float*)(arena + 39232);
    float*  b1s    = (float*)(arena + 39360);
    float*  maskrow= (float*)(arena + 39488);
    float*  Wf_s   = (float*)(arena + 39616);

    const int tid  = threadIdx.x;
    const int bt   = blockIdx.x >> 1;
    const int half = blockIdx.x & 1;
    const int b_ = bt >> 6, t_ = bt & 63;
    const float pw  = physw[0];
    const float rw_ = priorw[0];
    const float b2v = b2[0];

    const int m3 = tid & 31, n23 = tid >> 5;
    float4 e4[2];
    float pr5[2][5];
#pragma unroll
    for (int r = 0; r < 2; ++r) {
        int ng = half * 16 + n23 * 2 + r;
        e4[r] = *(const float4*)(edge + (((size_t)bt * 32 + ng) * 32 + m3) * 4);
        size_t pb = (((size_t)bt * 32 + ng) * 32 + m3) * 5;
#pragma unroll
        for (int j5 = 0; j5 < 5; ++j5) pr5[r][j5] = A_prior[pb + j5];
    }
#pragma unroll
    for (int it = 0; it < 2; ++it) {
        int f = tid + 256 * it;
        int lane9 = f & 63, ntk = f >> 6;
        int mm = lane9 & 15, qq = lane9 >> 4;
        int n = (ntk >> 2) * 16 + mm;
        int d = (ntk & 3) * 32 + qq * 8;
        const float* xr = x + ((size_t)((b_ * 32 + n) * 64 + t_)) * 128 + d;
        float4 a = *(const float4*)(xr);
        float4 b = *(const float4*)(xr + 4);
        uint4 pk;
        pk.x = pack2(a.x, a.y); pk.y = pack2(a.z, a.w);
        pk.z = pack2(b.x, b.y); pk.w = pack2(b.z, b.w);
        *(uint4*)(Zfrag + f * 8) = pk;
    }
    if (tid < 32) {
        int h = tid;
        W1e_s[h] = *(const float4*)(W1 + (size_t)h * 260 + 256);
        W2_s[h]  = W2[h];
        b1s[h]   = b1[h];
        maskrow[h] = pad_mask[b_ * 32 + h] ? 1.f : 0.f;
        if (h < 5) Wf_s[h] = Wfuse[h];
    }
    __syncthreads();

    const int wv = tid >> 6, lane = tid & 63;
    const int quad = lane >> 4, col0 = lane & 15;
    const bf16x8* Wf = (const bf16x8*)Wfrag;

    {
        const int Mtk = wv & 1;
        const int ng4 = (wv >> 1) * 4;
        f32x4 zero = {0.f, 0.f, 0.f, 0.f};
        f32x4 aK[4] = {zero, zero, zero, zero};
        f32x4 aV[4] = {zero, zero, zero, zero};
        f32x4 aQ[2] = {zero, zero};
        f32x4 aHq = zero, aHk = zero;
#pragma unroll
        for (int ks = 0; ks < 4; ++ks) {
            bf16x8 avK = *(const bf16x8*)(Zfrag + ((Mtk * 4 + ks) * 64 + lane) * 8);
            bf16x8 avQ = *(const bf16x8*)(Zfrag + ((half * 4 + ks) * 64 + lane) * 8);
#pragma unroll
            for (int nt = 0; nt < 4; ++nt) {
                int bi = ((ng4 + nt) * 4 + ks) * 64 + lane;
                aK[nt] = __builtin_amdgcn_mfma_f32_16x16x32_bf16(avK, Wf[bi + 2048], aK[nt], 0, 0, 0);
                aV[nt] = __builtin_amdgcn_mfma_f32_16x16x32_bf16(avK, Wf[bi + 4096], aV[nt], 0, 0, 0);
            }
#pragma unroll
            for (int nt = 0; nt < 2; ++nt) {
                int bq = ((wv * 2 + nt) * 4 + ks) * 64 + lane;
                aQ[nt] = __builtin_amdgcn_mfma_f32_16x16x32_bf16(avQ, Wf[bq], aQ[nt], 0, 0, 0);
            }
            if (wv < 2)
                aHq = __builtin_amdgcn_mfma_f32_16x16x32_bf16(avQ, Wf[8192 + (wv * 4 + ks) * 64 + lane], aHq, 0, 0, 0);
            aHk = __builtin_amdgcn_mfma_f32_16x16x32_bf16(avK, Wf[8704 + ((wv >> 1) * 4 + ks) * 64 + lane], aHk, 0, 0, 0);
        }
        __syncthreads();
#pragma unroll
        for (int nt = 0; nt < 4; ++nt) {
            int colc = (ng4 + nt) * 16 + col0;
            int vks = colc >> 5, vq = (colc >> 3) & 3, vj = colc & 7;
#pragma unroll
            for (int reg = 0; reg < 4; ++reg) {
                int row = Mtk * 16 + quad * 4 + reg;
                Ks[row * 132 + colc] = aK[nt][reg];
                int idx = (Mtk * 4 + vks) * 64 + vq * 16 + (quad * 4 + reg);
                Vfrag[idx * 8 + vj] = f2bf(aV[nt][reg]);
            }
        }
#pragma unroll
        for (int nt = 0; nt < 2; ++nt) {
            int colc = (wv * 2 + nt) * 16 + col0;
#pragma unroll
            for (int reg = 0; reg < 4; ++reg)
                Qs[(quad * 4 + reg) * 128 + colc] = aQ[nt][reg];
        }
        if (wv < 2) {
            int h = wv * 16 + col0;
#pragma unroll
            for (int reg = 0; reg < 4; ++reg)
                hqT[h * 18 + (quad * 4 + reg)] = f2bf(aHq[reg] + b1s[h]);
        }
        {
            int h = (wv >> 1) * 16 + col0;
#pragma unroll
            for (int reg = 0; reg < 4; ++reg)
                hks[(Mtk * 16 + quad * 4 + reg) * 34 + h] = f2bf(aHk[reg]);
        }
    }
    __syncthreads();

    {
        const int m = m3, n2 = n23;
        const float* krow = Ks + m * 132;
        const float* q0 = Qs + (n2 * 2) * 128;
        const float* q1 = Qs + (n2 * 2 + 1) * 128;
        float acc0 = 0.f, acc1 = 0.f;
        for (int j = 0; j < 128; j += 4) {
            float4 k4 = *(const float4*)(krow + j);
            float4 qa = *(const float4*)(q0 + j);
            float4 qb = *(const float4*)(q1 + j);
            acc0 = fmaf(qa.x, k4.x, fmaf(qa.y, k4.y, fmaf(qa.z, k4.z, fmaf(qa.w, k4.w, acc0))));
            acc1 = fmaf(qb.x, k4.x, fmaf(qb.y, k4.y, fmaf(qb.z, k4.z, fmaf(qb.w, k4.w, acc1))));
        }
        float pacc[2] = {0.f, 0.f};
        for (int h = 0; h < 32; ++h) {
            float4 we = W1e_s[h];
            float w2v = W2_s[h];
            float hkv = bf2f(hks[m * 34 + h]);
            float hq0 = bf2f(hqT[h * 18 + n2 * 2]);
            float hq1 = bf2f(hqT[h * 18 + n2 * 2 + 1]);
            float he0 = fmaf(e4[0].x, we.x, fmaf(e4[0].y, we.y, fmaf(e4[0].z, we.z, e4[0].w * we.w)));
            float he1 = fmaf(e4[1].x, we.x, fmaf(e4[1].y, we.y, fmaf(e4[1].z, we.z, e4[1].w * we.w)));
            pacc[0] = fmaf(fmaxf(hq0 + hkv + he0, 0.f), w2v, pacc[0]);
            pacc[1] = fmaf(fmaxf(hq1 + hkv + he1, 0.f), w2v, pacc[1]);
        }
        float cont[2] = {acc0, acc1};
#pragma unroll
        for (int r = 0; r < 2; ++r) {
            int nloc = n2 * 2 + r, ng = half * 16 + nloc;
            float pr = pr5[r][0]*Wf_s[0] + pr5[r][1]*Wf_s[1] + pr5[r][2]*Wf_s[2]
                     + pr5[r][3]*Wf_s[3] + pr5[r][4]*Wf_s[4];
            if (!(fabsf(pr) < 1e30f)) pr = 0.f;
            pr = fmaxf(pr, 0.f);
            float lg = cont[r] * 0.08838834764831845f
                     + pw * (pacc[r] + b2v) + rw_ * __logf(pr + 1e-6f);
            if (maskrow[ng] != 0.f || maskrow[m] != 0.f) lg = -1e9f;
            Lg[nloc * 33 + m] = lg;
        }
    }
    __syncthreads();

    if (tid < 16) {
        const int n = tid;
        float mx = -3.4e38f;
        for (int m2 = 0; m2 < 32; ++m2) mx = fmaxf(mx, Lg[n * 33 + m2]);
        float s = 0.f;
        for (int m2 = 0; m2 < 32; ++m2) {
            float e = __expf(Lg[n * 33 + m2] - mx);
            Lg[n * 33 + m2] = e; s += e;
        }
        float inv = 1.f / s;
        for (int m2 = 0; m2 < 32; ++m2) Lg[n * 33 + m2] *= inv;
    }
    __syncthreads();

    {
        const int d0 = (tid & 31) * 4, nl0 = (tid >> 5) * 2;
        const int vks = d0 >> 5, vq = (d0 >> 3) & 3, vj = d0 & 7;
        float sa[2][4] = {{0,0,0,0},{0,0,0,0}};
        for (int m = 0; m < 32; ++m) {
            int idx = ((m >> 4) * 4 + vks) * 64 + vq * 16 + (m & 15);
            const unsigned short* vp = Vfrag + idx * 8 + vj;
            float v0 = bf2f(vp[0]), v1 = bf2f(vp[1]), v2 = bf2f(vp[2]), v3 = bf2f(vp[3]);
            float a0 = Lg[nl0 * 33 + m], a1 = Lg[(nl0 + 1) * 33 + m];
            sa[0][0]=fmaf(a0,v0,sa[0][0]); sa[0][1]=fmaf(a0,v1,sa[0][1]);
            sa[0][2]=fmaf(a0,v2,sa[0][2]); sa[0][3]=fmaf(a0,v3,sa[0][3]);
            sa[1][0]=fmaf(a1,v0,sa[1][0]); sa[1][1]=fmaf(a1,v1,sa[1][1]);
            sa[1][2]=fmaf(a1,v2,sa[1][2]); sa[1][3]=fmaf(a1,v3,sa[1][3]);
        }
#pragma unroll
        for (int r = 0; r < 2; ++r) {
            int nloc = nl0 + r;
            unsigned short* sp = Sfrag + (vks * 64 + vq * 16 + nloc) * 8 + vj;
            sp[0] = f2bf(sa[r][0]); sp[1] = f2bf(sa[r][1]);
            sp[2] = f2bf(sa[r][2]); sp[3] = f2bf(sa[r][3]);
        }
    }
    __syncthreads();

    {
        f32x4 aT[2] = {{0.f,0.f,0.f,0.f},{0.f,0.f,0.f,0.f}};
#pragma unroll
        for (int ks = 0; ks < 4; ++ks) {
            bf16x8 av = *(const bf16x8*)(Sfrag + (ks * 64 + lane) * 8);
#pragma unroll
            for (int nt = 0; nt < 2; ++nt)
                aT[nt] = __builtin_amdgcn_mfma_f32_16x16x32_bf16(
                    av, Wf[6144 + ((wv * 2 + nt) * 4 + ks) * 64 + lane], aT[nt], 0, 0, 0);
        }
#pragma unroll
        for (int nt = 0; nt < 2; ++nt) {
            int colc = (wv * 2 + nt) * 16 + col0;
#pragma unroll
            for (int reg = 0; reg < 4; ++reg)
                ThOut[(quad * 4 + reg) * 128 + colc] = aT[nt][reg];
        }
    }
    __syncthreads();

    {
        const int d0 = (tid & 31) * 4, n2 = tid >> 5;
        float4 g4  = *(const float4*)(gma + d0);
        float4 be4 = *(const float4*)(bta + d0);
#pragma unroll
        for (int r = 0; r < 2; ++r) {
            int nloc = n2 * 2 + r, ng = half * 16 + nloc;
            const float* xr = x + ((size_t)((b_ * 32 + ng) * 64 + t_)) * 128 + d0;
            float4 z  = *(const float4*)(xr);
            float4 th = *(const float4*)(ThOut + nloc * 128 + d0);
            float y0 = th.x + z.x, y1 = th.y + z.y, y2 = th.z + z.z, y3 = th.w + z.w;
            float s  = (y0 + y1) + (y2 + y3);
            float s2 = (y0*y0 + y1*y1) + (y2*y2 + y3*y3);
#pragma unroll
            for (int off = 1; off < 32; off <<= 1) {
                s  += __shfl_xor(s,  off, 64);
                s2 += __shfl_xor(s2, off, 64);
            }
            float mu   = s * 0.0078125f;
            float var  = s2 * 0.0078125f - mu * mu;
            float rstd = rsqrtf(var + 1e-5f);
            float msk  = (maskrow[ng] != 0.f) ? 0.f : 1.f;
            float4 o;
            o.x = ((y0 - mu) * rstd * g4.x + be4.x) * msk;
            o.y = ((y1 - mu) * rstd * g4.y + be4.y) * msk;
            o.z = ((y2 - mu) * rstd * g4.z + be4.z) * msk;
            o.w = ((y3 - mu) * rstd * g4.w + be4.w) * msk;
            *(float4*)(out + ((size_t)((b_ * 32 + ng) * 64 + t_)) * 128 + d0) = o;
        }
    }
}

// ===========================================================================
extern "C" void kernel_launch(void* const* d_in, const int* in_sizes, int n_in,
                              void* d_out, int out_size, void* d_ws, size_t ws_size,
                              hipStream_t stream) {
    const float* x        = (const float*)d_in[0];
    const float* edge     = (const float*)d_in[1];
    const float* A_prior  = (const float*)d_in[2];
    const unsigned char* pad_mask = (const unsigned char*)d_in[3];
    const float* Wq       = (const float*)d_in[4];
    const float* Wk       = (const float*)d_in[5];
    const float* Wv       = (const float*)d_in[6];
    const float* Theta    = (const float*)d_in[7];
    const float* Wfuse    = (const float*)d_in[8];
    const float* W1       = (const float*)d_in[9];
    const float* b1       = (const float*)d_in[10];
    const float* W2       = (const float*)d_in[11];
    const float* b2       = (const float*)d_in[12];
    const float* gma      = (const float*)d_in[13];
    const float* bta      = (const float*)d_in[14];
    const float* physw    = (const float*)d_in[15];
    const float* priorw   = (const float*)d_in[16];
    float* out = (float*)d_out;

    unsigned short* Wfrag = (unsigned short*)d_ws;   // 147456 B

    // workspace layout (fast path):
    //   [0,147456)            Wfrag
    //   +8388608              Qws   fp32 [16384][128]
    //   +8388608              Kws   fp32 [16384][128]
    //   +4194304              Vws   bf16 [16384][128]
    //   +1048576              hqws  bf16 [16384][32]
    //   +1048576              hkws  bf16 [16384][32]
    const size_t NEED = 147456ull + 8388608ull * 2 + 4194304ull + 1048576ull * 2; // 23216128

    if (ws_size >= NEED) {
        float* Qws = (float*)((char*)d_ws + 147456);
        float* Kws = (float*)((char*)d_ws + 147456 + 8388608ull);
        unsigned short* Vws  = (unsigned short*)((char*)d_ws + 147456 + 16777216ull);
        unsigned short* hqws = (unsigned short*)((char*)d_ws + 147456 + 16777216ull + 4194304ull);
        unsigned short* hkws = hqws + (size_t)16384 * 32;

        k0_prep<<<dim3(64), dim3(256), 0, stream>>>(Wq, Wk, Wv, Theta, W1, Wfrag);
        k1_proj<<<dim3(256), dim3(256), 0, stream>>>(x, Wfrag, b1, Qws, Kws, Vws, hqws, hkws);
        k2_attn<<<dim3(512), dim3(256), 0, stream>>>(
            x, edge, A_prior, pad_mask, Wfrag, Wfuse, W1, W2, b2,
            gma, bta, physw, priorw, Qws, Kws, Vws, hqws, hkws, out);
    } else {
        // R9 fallback
        k0a_pack_w<<<dim3(32), dim3(256), 0, stream>>>(Wq, Wk, Wv, Theta, Wfrag);
        k0b_compose<<<dim3(8), dim3(256), 0, stream>>>(Wq, Wk, W1, Wfrag);
        gnn_fused<<<dim3(1024), dim3(256), 0, stream>>>(
            x, edge, A_prior, pad_mask, Wfrag, Wfuse,
            W1, b1, W2, b2, gma, bta, physw, priorw, out);
    }
}

// Round 2
// 293.050 us; speedup vs baseline: 1.0906x; 1.0906x over previous
//
#include <hip/hip_runtime.h>

// B=8, N=32, T=64, D=128, E=4, H=32, BT=512
// R11: kill scratch traffic. R10 post-mortem: dur == (FETCH+WRITE)/3TB/s in both
// R9 and R10; WRITE ~327MB with only 8.4MB of real stores and VGPR_Count 84
// against ~150-word live sets => register arrays demoted/spilled to scratch,
// re-read in loops. Fixes: launch_bounds(256,2) (256-VGPR budget; grid gives
// 2 blocks/CU anyway), hq/hk via LDS (stride-34, conflict-free) instead of
// 64-word register prefetch, prior folded at load (4 regs), k1 loads B-frags
// direct from L2-resident Wfrag (LDS staging removed; frags are per-wave
// disjoint so LDS sharing gained nothing), 32-token k1 blocks -> 2 blocks/CU.

typedef __bf16 bf16x8 __attribute__((ext_vector_type(8)));
typedef float  f32x4  __attribute__((ext_vector_type(4)));

static __device__ __forceinline__ unsigned short f2bf(float f) {
    unsigned u = __float_as_uint(f);
    u += 0x7fffu + ((u >> 16) & 1u);        // RNE
    return (unsigned short)(u >> 16);
}
static __device__ __forceinline__ float bf2f(unsigned short u) {
    return __uint_as_float(((unsigned)u) << 16);
}
static __device__ __forceinline__ unsigned pack2(float a, float b) {
    return (unsigned)f2bf(a) | ((unsigned)f2bf(b) << 16);
}

// ---------------------------------------------------------------------------
// Wfrag (16B chunks): [0,2048) Wq | [2048,4096) Wk | [4096,6144) Wv |
// [6144,8192) Theta | chunk 8192+: Cq=W1q@Wq (512), chunk 8704+: Ck=W1k@Wk (512).
// B-frag chunk (nt*4+ks)*64+lane holds B[k=j][n]: n = nt*16+(lane&15),
// j = ks*32+(lane>>4)*8 + (0..7).
// ---------------------------------------------------------------------------

__global__ __launch_bounds__(256) void k0_prep(
    const float* __restrict__ Wq, const float* __restrict__ Wk,
    const float* __restrict__ Wv, const float* __restrict__ Theta,
    const float* __restrict__ W1, unsigned short* __restrict__ Wfrag)
{
    const int tid = threadIdx.x;
    if (blockIdx.x < 32) {
        int gid = blockIdx.x * 256 + tid;      // 0..8191
        int g = gid >> 11, c = gid & 2047;
        int ntk = c >> 6, lane = c & 63;
        int i = (ntk >> 2) * 16 + (lane & 15);
        int j = (ntk & 3) * 32 + (lane >> 4) * 8;
        const float* src = (g == 0 ? Wq : g == 1 ? Wk : g == 2 ? Wv : Theta) + (size_t)i * 128 + j;
        float4 a = *(const float4*)(src);
        float4 b = *(const float4*)(src + 4);
        uint4 pk;
        pk.x = pack2(a.x, a.y); pk.y = pack2(a.z, a.w);
        pk.z = pack2(b.x, b.y); pk.w = pack2(b.z, b.w);
        *(uint4*)(Wfrag + (size_t)gid * 8) = pk;
    } else {
        // compose Cq = W1q@Wq, Ck = W1k@Wk
        int b2 = blockIdx.x - 32;              // 0..31
        int mat = b2 & 1;
        int hbase = (b2 >> 1) * 2;
        int hl = tid >> 7, col = tid & 127;
        int h = hbase + hl;
        const float* Wsel = mat ? Wk : Wq;
        const float* w1r = W1 + (size_t)h * 260 + mat * 128;
        float acc = 0.f;
        for (int i = 0; i < 128; ++i)
            acc = fmaf(w1r[i], Wsel[(size_t)i * 128 + col], acc);
        int nt = h >> 4;
        unsigned base = 65536u + (unsigned)mat * 4096u;   // shorts
        int lane = (h & 15) | (((col >> 3) & 3) << 4);
        int ks = col >> 5, vj = col & 7;
        Wfrag[base + (unsigned)((nt * 4 + ks) * 64 + lane) * 8 + vj] = f2bf(acc);
    }
}

// ===== projection GEMM: M=16384 tokens, N=448 (Q|K|V|hq|hk), K=128 ==========
// grid 512 x 256 (32 tokens/block, 2 blocks/CU). B-frags are per-wave disjoint:
// load straight from Wfrag (L2-resident 144KB) into registers, no LDS stage.
__global__ __launch_bounds__(256, 1)
void k1_proj(const float* __restrict__ x,
             const unsigned short* __restrict__ Wfrag,
             const float* __restrict__ b1,
             float* __restrict__ Qws, float* __restrict__ Kws,
             unsigned short* __restrict__ Vws,
             unsigned short* __restrict__ hqws, unsigned short* __restrict__ hkws)
{
    __shared__ __align__(16) unsigned short Zf[512 * 8];     // 8 KB
    const int tid = threadIdx.x;
    const int Mbase = blockIdx.x * 32;

    // stage Z bf16 A-frags for 32 tokens (identical packing to R9/R10)
#pragma unroll
    for (int it = 0; it < 2; ++it) {
        int f = tid + 256 * it;                 // chunk 0..511
        int lane9 = f & 63, tk = f >> 6;        // tk 0..7
        int nl = (tk >> 2) * 16 + (lane9 & 15); // token-local 0..31
        int d  = (tk & 3) * 32 + (lane9 >> 4) * 8;
        int tok = Mbase + nl;
        int n = tok & 31, bt = tok >> 5;
        int b_ = bt >> 6, t_ = bt & 63;
        const float* xr = x + ((size_t)((b_ * 32 + n) * 64 + t_)) * 128 + d;
        float4 a = *(const float4*)(xr);
        float4 b = *(const float4*)(xr + 4);
        uint4 pk;
        pk.x = pack2(a.x, a.y); pk.y = pack2(a.z, a.w);
        pk.z = pack2(b.x, b.y); pk.w = pack2(b.z, b.w);
        *(uint4*)(Zf + f * 8) = pk;
    }

    const int wv = tid >> 6, lane = tid & 63;
    const int quad = lane >> 4, col0 = lane & 15;
    const float b1lo = b1[col0], b1hi = b1[16 + col0];
    const bf16x8* Wf = (const bf16x8*)Wfrag;

    // prefetch all 28 B-frags for this wave's nt set {wv, wv+4, ..., wv+24}
    bf16x8 wfr[28];
#pragma unroll
    for (int k7 = 0; k7 < 7; ++k7) {
        const int nt = wv + k7 * 4;
        const int cbase = (nt < 24) ? nt * 256 : 8192 + (nt - 24) * 256;
#pragma unroll
        for (int ks = 0; ks < 4; ++ks)
            wfr[k7 * 4 + ks] = Wf[cbase + ks * 64 + lane];
    }
    __syncthreads();

    bf16x8 avZ[2][4];   // [token-group][ks]
#pragma unroll
    for (int tg = 0; tg < 2; ++tg)
#pragma unroll
        for (int ks = 0; ks < 4; ++ks)
            avZ[tg][ks] = *(const bf16x8*)(Zf + ((tg * 4 + ks) * 64 + lane) * 8);

    const f32x4 zero = {0.f, 0.f, 0.f, 0.f};
#pragma unroll
    for (int k7 = 0; k7 < 7; ++k7) {
        const int nt = wv + k7 * 4;             // wave-uniform
        f32x4 acc[2] = {zero, zero};
#pragma unroll
        for (int ks = 0; ks < 4; ++ks) {
            bf16x8 bw = wfr[k7 * 4 + ks];
#pragma unroll
            for (int tg = 0; tg < 2; ++tg)
                acc[tg] = __builtin_amdgcn_mfma_f32_16x16x32_bf16(avZ[tg][ks], bw, acc[tg], 0, 0, 0);
        }
#pragma unroll
        for (int tg = 0; tg < 2; ++tg) {
            int tokb = Mbase + tg * 16 + quad * 4;
#pragma unroll
            for (int reg = 0; reg < 4; ++reg) {
                size_t tok = (size_t)(tokb + reg);
                float v = acc[tg][reg];
                if (nt < 8)       Qws[tok * 128 + nt * 16 + col0] = v;
                else if (nt < 16) Kws[tok * 128 + (nt - 8) * 16 + col0] = v;
                else if (nt < 24) Vws[tok * 128 + (nt - 16) * 16 + col0] = f2bf(v);
                else if (nt < 26) hqws[tok * 32 + (nt - 24) * 16 + col0] = f2bf(v + (nt == 24 ? b1lo : b1hi));
                else              hkws[tok * 32 + (nt - 26) * 16 + col0] = f2bf(v);
            }
        }
    }
}

// ===== per-bt attention epilogue. grid 512 x 256, 2 blocks/CU ===============
__global__ __launch_bounds__(256, 2)
void k2_attn(const float* __restrict__ x, const float* __restrict__ edge,
             const float* __restrict__ A_prior, const unsigned char* __restrict__ pad_mask,
             const unsigned short* __restrict__ Wfrag, const float* __restrict__ Wfuse,
             const float* __restrict__ W1, const float* __restrict__ W2,
             const float* __restrict__ b2, const float* __restrict__ gma,
             const float* __restrict__ bta, const float* __restrict__ physw,
             const float* __restrict__ priorw,
             const float* __restrict__ Qws, const float* __restrict__ Kws,
             const unsigned short* __restrict__ Vws,
             const unsigned short* __restrict__ hqws, const unsigned short* __restrict__ hkws,
             float* __restrict__ out)
{
    __shared__ __align__(16) unsigned char arena[51744];
    float* Qs = (float*)arena;                                // [32][132] fp32
    float* Ks = (float*)(arena + 16896);                      // [32][132] fp32
    unsigned short* Sfrag = (unsigned short*)(arena + 16896); // alias Ks (P6+)
    unsigned short* Vs = (unsigned short*)(arena + 33792);    // [32][128] bf16
    float* Lg = (float*)(arena + 41984);                      // [32][36]
    unsigned short* hqL = (unsigned short*)(arena + 46592);   // [32][34] bf16
    unsigned short* hkL = (unsigned short*)(arena + 48768);   // [32][34] bf16
    float4* W1e_s  = (float4*)(arena + 50944);
    float*  W2_s   = (float*)(arena + 51456);
    float*  maskrow= (float*)(arena + 51584);
    float*  Wf_s   = (float*)(arena + 51712);
    float*  ThOut  = Qs;                                      // alias Qs (P7+), stride 132

    const int tid = threadIdx.x;
    const int bt  = blockIdx.x;
    const int b_ = bt >> 6, t_ = bt & 63;
    const float pw  = physw[0];
    const float rw_ = priorw[0];
    const float b2v = b2[0];

    // ---- P0: stage Q,K (fp32) / V (bf16) / hq,hk (bf16, stride 34) ----
    {
        const int row = tid >> 3, cl = (tid & 7) * 4;
        const size_t gb = ((size_t)bt * 32 + row) * 128;
#pragma unroll
        for (int c = 0; c < 4; ++c) {
            int off = cl + c * 32;
            *(float4*)(Qs + row * 132 + off) = *(const float4*)(Qws + gb + off);
            *(float4*)(Ks + row * 132 + off) = *(const float4*)(Kws + gb + off);
        }
        const int vl = (tid & 7) * 8;
#pragma unroll
        for (int c = 0; c < 2; ++c) {
            int off = vl + c * 64;
            *(uint4*)(Vs + row * 128 + off) = *(const uint4*)(Vws + gb + off);
        }
    }
    if (tid < 64) {
        const int row = tid & 31;
        const unsigned short* src = (tid < 32 ? hqws : hkws) + ((size_t)bt * 32 + row) * 32;
        unsigned* dstU = (unsigned*)((tid < 32 ? hqL : hkL) + row * 34);
        const uint4* s4 = (const uint4*)src;
#pragma unroll
        for (int i = 0; i < 4; ++i) {
            uint4 w = s4[i];
            dstU[i * 4 + 0] = w.x; dstU[i * 4 + 1] = w.y;
            dstU[i * 4 + 2] = w.z; dstU[i * 4 + 3] = w.w;
        }
    }
    if (tid < 32) {
        int h = tid;
        W1e_s[h] = *(const float4*)(W1 + (size_t)h * 260 + 256);
        W2_s[h]  = W2[h];
        maskrow[h] = pad_mask[b_ * 32 + h] ? 1.f : 0.f;
        if (h < 5) Wf_s[h] = Wfuse[h];
    }
    __syncthreads();

    // ---- P3: logits; thread covers (n in {2npg, 2npg+1}) x (m in {mp, mp+16})
    {
        const int mp = tid & 15, npg = tid >> 4;
        const int n0 = npg * 2, mA = mp, mB = mp + 16;

        float4 e4[2][2];
        float  prv[2][2];           // rw_ * log(clip(prior)+1e-6), folded at load
#pragma unroll
        for (int r = 0; r < 2; ++r)
#pragma unroll
            for (int c = 0; c < 2; ++c) {
                int m = c ? mB : mA;
                e4[r][c] = *(const float4*)(edge + (((size_t)bt * 32 + (n0 + r)) * 32 + m) * 4);
                const float* pp = A_prior + (((size_t)bt * 32 + (n0 + r)) * 32 + m) * 5;
                float p0 = pp[0], p1 = pp[1], p2 = pp[2], p3 = pp[3], p4 = pp[4];
                float pr = p0*Wf_s[0] + p1*Wf_s[1] + p2*Wf_s[2] + p3*Wf_s[3] + p4*Wf_s[4];
                if (!(fabsf(pr) < 1e30f)) pr = 0.f;
                pr = fmaxf(pr, 0.f);
                prv[r][c] = rw_ * __logf(pr + 1e-6f);
            }

        const float* qa = Qs + n0 * 132;
        const float* qb = qa + 132;
        const float* ka = Ks + mA * 132;
        const float* kb = Ks + mB * 132;
        float a00 = 0.f, a01 = 0.f, a10 = 0.f, a11 = 0.f;
        for (int j = 0; j < 128; j += 4) {
            float4 kva = *(const float4*)(ka + j);
            float4 kvb = *(const float4*)(kb + j);
            float4 qva = *(const float4*)(qa + j);
            float4 qvb = *(const float4*)(qb + j);
            a00 = fmaf(qva.x, kva.x, fmaf(qva.y, kva.y, fmaf(qva.z, kva.z, fmaf(qva.w, kva.w, a00))));
            a01 = fmaf(qva.x, kvb.x, fmaf(qva.y, kvb.y, fmaf(qva.z, kvb.z, fmaf(qva.w, kvb.w, a01))));
            a10 = fmaf(qvb.x, kva.x, fmaf(qvb.y, kva.y, fmaf(qvb.z, kva.z, fmaf(qvb.w, kva.w, a10))));
            a11 = fmaf(qvb.x, kvb.x, fmaf(qvb.y, kvb.y, fmaf(qvb.z, kvb.z, fmaf(qvb.w, kvb.w, a11))));
        }
        float pacc[2][2] = {{0.f, 0.f}, {0.f, 0.f}};
#pragma unroll
        for (int h = 0; h < 32; ++h) {
            float4 we = W1e_s[h];
            float w2v = W2_s[h];
            float hq0 = bf2f(hqL[n0 * 34 + h]);
            float hq1 = bf2f(hqL[(n0 + 1) * 34 + h]);
            float hkA = bf2f(hkL[mA * 34 + h]);
            float hkB = bf2f(hkL[mB * 34 + h]);
#pragma unroll
            for (int r = 0; r < 2; ++r) {
                float hqv = r ? hq1 : hq0;
#pragma unroll
                for (int c = 0; c < 2; ++c) {
                    float hkv = c ? hkB : hkA;
                    float4 e = e4[r][c];
                    float he = fmaf(e.x, we.x, fmaf(e.y, we.y, fmaf(e.z, we.z, e.w * we.w)));
                    pacc[r][c] = fmaf(fmaxf(hqv + hkv + he, 0.f), w2v, pacc[r][c]);
                }
            }
        }
        float cont[2][2] = {{a00, a01}, {a10, a11}};
#pragma unroll
        for (int r = 0; r < 2; ++r)
#pragma unroll
            for (int c = 0; c < 2; ++c) {
                int n = n0 + r, m = c ? mB : mA;
                float lg = cont[r][c] * 0.08838834764831845f
                         + pw * (pacc[r][c] + b2v) + prv[r][c];
                if (maskrow[n] != 0.f || maskrow[m] != 0.f) lg = -1e9f;
                Lg[n * 36 + m] = lg;
            }
    }
    __syncthreads();

    // ---- P4: softmax (32 rows) ----
    if (tid < 32) {
        const int n = tid;
        float mx = -3.4e38f;
        for (int m2 = 0; m2 < 32; ++m2) mx = fmaxf(mx, Lg[n * 36 + m2]);
        float s = 0.f;
        for (int m2 = 0; m2 < 32; ++m2) {
            float e = __expf(Lg[n * 36 + m2] - mx);
            Lg[n * 36 + m2] = e; s += e;
        }
        float inv = 1.f / s;
        for (int m2 = 0; m2 < 32; ++m2) Lg[n * 36 + m2] *= inv;
    }
    __syncthreads();

    const int wv = tid >> 6, lane = tid & 63;
    const int quad = lane >> 4, col0 = lane & 15;
    const int rg = wv & 1, ch = wv >> 1;

    // ---- P6: Theta-frag prefetch (global, L2/L3) + spatial = alpha @ V ----
    bf16x8 thf[16];
    {
        const bf16x8* Wf = (const bf16x8*)Wfrag;
#pragma unroll
        for (int nt = 0; nt < 4; ++nt)
#pragma unroll
            for (int ks = 0; ks < 4; ++ks)
                thf[nt * 4 + ks] = Wf[6144 + (((ch * 4 + nt) * 4 + ks) * 64) + lane];
    }
    {
        const int d0 = (tid & 31) * 4, ng = tid >> 5;   // 4 rows/thread: ng*4+r
        const int vks = d0 >> 5, vq = (d0 >> 3) & 3, vj = d0 & 7;
        float sa[4][4] = {};
        for (int m = 0; m < 32; m += 4) {
            float alv[4][4];
#pragma unroll
            for (int r = 0; r < 4; ++r) {
                float4 t = *(const float4*)(Lg + (ng * 4 + r) * 36 + m);
                alv[r][0] = t.x; alv[r][1] = t.y; alv[r][2] = t.z; alv[r][3] = t.w;
            }
#pragma unroll
            for (int mm = 0; mm < 4; ++mm) {
                const unsigned short* vp = Vs + (m + mm) * 128 + d0;
                float v0 = bf2f(vp[0]), v1 = bf2f(vp[1]), v2 = bf2f(vp[2]), v3 = bf2f(vp[3]);
#pragma unroll
                for (int r = 0; r < 4; ++r) {
                    float a = alv[r][mm];
                    sa[r][0] = fmaf(a, v0, sa[r][0]); sa[r][1] = fmaf(a, v1, sa[r][1]);
                    sa[r][2] = fmaf(a, v2, sa[r][2]); sa[r][3] = fmaf(a, v3, sa[r][3]);
                }
            }
        }
        // Sfrag aliases Ks (dead after P3); all threads are past the P4 barrier.
#pragma unroll
        for (int r = 0; r < 4; ++r) {
            int nloc = ng * 4 + r;
            int tg = nloc >> 4, nl = nloc & 15;
            unsigned short* sp = Sfrag + ((tg * 4 + vks) * 64 + vq * 16 + nl) * 8 + vj;
            sp[0] = f2bf(sa[r][0]); sp[1] = f2bf(sa[r][1]);
            sp[2] = f2bf(sa[r][2]); sp[3] = f2bf(sa[r][3]);
        }
    }
    __syncthreads();

    // ---- P7: Theta MFMA -> ThOut (alias Qs, stride 132) ----
    {
        const f32x4 zero = {0.f, 0.f, 0.f, 0.f};
        f32x4 aT[4] = {zero, zero, zero, zero};
#pragma unroll
        for (int ks = 0; ks < 4; ++ks) {
            bf16x8 av = *(const bf16x8*)(Sfrag + ((rg * 4 + ks) * 64 + lane) * 8);
#pragma unroll
            for (int nt = 0; nt < 4; ++nt)
                aT[nt] = __builtin_amdgcn_mfma_f32_16x16x32_bf16(av, thf[nt * 4 + ks], aT[nt], 0, 0, 0);
        }
#pragma unroll
        for (int nt = 0; nt < 4; ++nt) {
            int colc = ch * 64 + nt * 16 + col0;
#pragma unroll
            for (int reg = 0; reg < 4; ++reg)
                ThOut[(rg * 16 + quad * 4 + reg) * 132 + colc] = aT[nt][reg];
        }
    }
    __syncthreads();

    // ---- P8: y = x + ThOut; LayerNorm; mask; store (4 rows/thread) ----
    {
        const int d0 = (tid & 31) * 4, ng = tid >> 5;
        float4 g4  = *(const float4*)(gma + d0);
        float4 be4 = *(const float4*)(bta + d0);
#pragma unroll
        for (int r = 0; r < 4; ++r) {
            int nloc = ng * 4 + r;
            const float* xr = x + ((size_t)((b_ * 32 + nloc) * 64 + t_)) * 128 + d0;
            float4 z  = *(const float4*)(xr);
            float4 th = *(const float4*)(ThOut + nloc * 132 + d0);
            float y0 = th.x + z.x, y1 = th.y + z.y, y2 = th.z + z.z, y3 = th.w + z.w;
            float s  = (y0 + y1) + (y2 + y3);
            float s2 = (y0*y0 + y1*y1) + (y2*y2 + y3*y3);
#pragma unroll
            for (int off = 1; off < 32; off <<= 1) {
                s  += __shfl_xor(s,  off, 64);
                s2 += __shfl_xor(s2, off, 64);
            }
            float mu   = s * 0.0078125f;
            float var  = s2 * 0.0078125f - mu * mu;
            float rstd = rsqrtf(var + 1e-5f);
            float msk  = (maskrow[nloc] != 0.f) ? 0.f : 1.f;
            float4 o;
            o.x = ((y0 - mu) * rstd * g4.x + be4.x) * msk;
            o.y = ((y1 - mu) * rstd * g4.y + be4.y) * msk;
            o.z = ((y2 - mu) * rstd * g4.z + be4.z) * msk;
            o.w = ((y3 - mu) * rstd * g4.w + be4.w) * msk;
            *(float4*)(out + ((size_t)((b_ * 32 + nloc) * 64 + t_)) * 128 + d0) = o;
        }
    }
}

// ===========================================================================
// ===== R9 FALLBACK PATH (used only if ws_size is too small) ================
// ===========================================================================
__global__ __launch_bounds__(256) void k0a_pack_w(
    const float* __restrict__ Wq, const float* __restrict__ Wk,
    const float* __restrict__ Wv, const float* __restrict__ Theta,
    unsigned short* __restrict__ Wfrag)
{
    int gid = blockIdx.x * 256 + threadIdx.x;      // 0..8191
    int g = gid >> 11, c = gid & 2047;
    int ntk = c >> 6, lane = c & 63;
    int i = (ntk >> 2) * 16 + (lane & 15);
    int j = (ntk & 3) * 32 + (lane >> 4) * 8;
    const float* src = (g == 0 ? Wq : g == 1 ? Wk : g == 2 ? Wv : Theta) + (size_t)i * 128 + j;
    float4 a = *(const float4*)(src);
    float4 b = *(const float4*)(src + 4);
    uint4 pk;
    pk.x = pack2(a.x, a.y); pk.y = pack2(a.z, a.w);
    pk.z = pack2(b.x, b.y); pk.w = pack2(b.z, b.w);
    *(uint4*)(Wfrag + (size_t)gid * 8) = pk;
}

__global__ __launch_bounds__(256, 1) void k0b_compose(
    const float* __restrict__ Wq, const float* __restrict__ Wk,
    const float* __restrict__ W1, unsigned short* __restrict__ Wfrag)
{
    __shared__ __align__(16) float Ws[128 * 132];
    __shared__ __align__(16) float W1s[8 * 128];
    const int tid = threadIdx.x;
    const int mat   = blockIdx.x & 1;
    const int hbase = (blockIdx.x >> 1) * 8;
    const float* Wsel = mat ? Wk : Wq;
#pragma unroll
    for (int q = 0; q < 16; ++q) {
        int f = tid + 256 * q;
        int i = f >> 5, c4 = (f & 31) * 4;
        *(float4*)(Ws + i * 132 + c4) = *(const float4*)(Wsel + (size_t)i * 128 + c4);
    }
#pragma unroll
    for (int q = 0; q < 4; ++q) {
        int f = tid + 256 * q;
        int hl = f >> 7, i = f & 127;
        W1s[hl * 128 + i] = W1[(size_t)(hbase + hl) * 260 + mat * 128 + i];
    }
    __syncthreads();
    const int hl = tid >> 5;
    const int h  = hbase + hl;
    const int j0 = (tid & 31) * 4;
    float4 acc = {0.f, 0.f, 0.f, 0.f};
    for (int i = 0; i < 128; ++i) {
        float c = W1s[hl * 128 + i];
        float4 w = *(const float4*)(Ws + i * 132 + j0);
        acc.x = fmaf(c, w.x, acc.x); acc.y = fmaf(c, w.y, acc.y);
        acc.z = fmaf(c, w.z, acc.z); acc.w = fmaf(c, w.w, acc.w);
    }
    const int nt = h >> 4;
    const unsigned base = 65536u + (unsigned)mat * 4096u;   // shorts
    float av[4] = {acc.x, acc.y, acc.z, acc.w};
#pragma unroll
    for (int jj = 0; jj < 4; ++jj) {
        int j = j0 + jj;
        int lane = (h & 15) | (((j >> 3) & 3) << 4);
        int ks = j >> 5, vj = j & 7;
        Wfrag[base + (unsigned)((nt * 4 + ks) * 64 + lane) * 8 + vj] = f2bf(av[jj]);
    }
}

__global__ __launch_bounds__(256, 4)
void gnn_fused(const float* __restrict__ x,
               const float* __restrict__ edge,
               const float* __restrict__ A_prior,
               const unsigned char* __restrict__ pad_mask,
               const unsigned short* __restrict__ Wfrag,
               const float* __restrict__ Wfuse,
               const float* __restrict__ W1,
               const float* __restrict__ b1,
               const float* __restrict__ W2,
               const float* __restrict__ b2,
               const float* __restrict__ gma,
               const float* __restrict__ bta,
               const float* __restrict__ physw,
               const float* __restrict__ priorw,
               float* __restrict__ out)
{
    __shared__ __align__(16) unsigned char arena[39648];
    unsigned short* Zfrag = (unsigned short*)(arena);
    float*          Qs    = (float*)(arena);
    unsigned short* Sfrag = (unsigned short*)(arena);
    float*          Ks    = (float*)(arena + 8192);
    unsigned short* Vfrag = (unsigned short*)(arena + 25088);
    float*          ThOut = (float*)(arena + 25088);
    float*          Lg    = (float*)(arena + 33280);
    unsigned short* hqT   = (unsigned short*)(arena + 35392);
    unsigned short* hks   = (unsigned short*)(arena + 36544);
    float4* W1e_s  = (float4*)(arena + 38720);
    float*  W2_s   = (float*)(arena + 39232);
    float*  b1s    = (float*)(arena + 39360);
    float*  maskrow= (float*)(arena + 39488);
    float*  Wf_s   = (float*)(arena + 39616);

    const int tid  = threadIdx.x;
    const int bt   = blockIdx.x >> 1;
    const int half = blockIdx.x & 1;
    const int b_ = bt >> 6, t_ = bt & 63;
    const float pw  = physw[0];
    const float rw_ = priorw[0];
    const float b2v = b2[0];

    const int m3 = tid & 31, n23 = tid >> 5;
    float4 e4[2];
    float pr5[2][5];
#pragma unroll
    for (int r = 0; r < 2; ++r) {
        int ng = half * 16 + n23 * 2 + r;
        e4[r] = *(const float4*)(edge + (((size_t)bt * 32 + ng) * 32 + m3) * 4);
        size_t pb = (((size_t)bt * 32 + ng) * 32 + m3) * 5;
#pragma unroll
        for (int j5 = 0; j5 < 5; ++j5) pr5[r][j5] = A_prior[pb + j5];
    }
#pragma unroll
    for (int it = 0; it < 2; ++it) {
        int f = tid + 256 * it;
        int lane9 = f & 63, ntk = f >> 6;
        int mm = lane9 & 15, qq = lane9 >> 4;
        int n = (ntk >> 2) * 16 + mm;
        int d = (ntk & 3) * 32 + qq * 8;
        const float* xr = x + ((size_t)((b_ * 32 + n) * 64 + t_)) * 128 + d;
        float4 a = *(const float4*)(xr);
        float4 b = *(const float4*)(xr + 4);
        uint4 pk;
        pk.x = pack2(a.x, a.y); pk.y = pack2(a.z, a.w);
        pk.z = pack2(b.x, b.y); pk.w = pack2(b.z, b.w);
        *(uint4*)(Zfrag + f * 8) = pk;
    }
    if (tid < 32) {
        int h = tid;
        W1e_s[h] = *(const float4*)(W1 + (size_t)h * 260 + 256);
        W2_s[h]  = W2[h];
        b1s[h]   = b1[h];
        maskrow[h] = pad_mask[b_ * 32 + h] ? 1.f : 0.f;
        if (h < 5) Wf_s[h] = Wfuse[h];
    }
    __syncthreads();

    const int wv = tid >> 6, lane = tid & 63;
    const int quad = lane >> 4, col0 = lane & 15;
    const bf16x8* Wf = (const bf16x8*)Wfrag;

    {
        const int Mtk = wv & 1;
        const int ng4 = (wv >> 1) * 4;
        f32x4 zero = {0.f, 0.f, 0.f, 0.f};
        f32x4 aK[4] = {zero, zero, zero, zero};
        f32x4 aV[4] = {zero, zero, zero, zero};
        f32x4 aQ[2] = {zero, zero};
        f32x4 aHq = zero, aHk = zero;
#pragma unroll
        for (int ks = 0; ks < 4; ++ks) {
            bf16x8 avK = *(const bf16x8*)(Zfrag + ((Mtk * 4 + ks) * 64 + lane) * 8);
            bf16x8 avQ = *(const bf16x8*)(Zfrag + ((half * 4 + ks) * 64 + lane) * 8);
#pragma unroll
            for (int nt = 0; nt < 4; ++nt) {
                int bi = ((ng4 + nt) * 4 + ks) * 64 + lane;
                aK[nt] = __builtin_amdgcn_mfma_f32_16x16x32_bf16(avK, Wf[bi + 2048], aK[nt], 0, 0, 0);
                aV[nt] = __builtin_amdgcn_mfma_f32_16x16x32_bf16(avK, Wf[bi + 4096], aV[nt], 0, 0, 0);
            }
#pragma unroll
            for (int nt = 0; nt < 2; ++nt) {
                int bq = ((wv * 2 + nt) * 4 + ks) * 64 + lane;
                aQ[nt] = __builtin_amdgcn_mfma_f32_16x16x32_bf16(avQ, Wf[bq], aQ[nt], 0, 0, 0);
            }
            if (wv < 2)
                aHq = __builtin_amdgcn_mfma_f32_16x16x32_bf16(avQ, Wf[8192 + (wv * 4 + ks) * 64 + lane], aHq, 0, 0, 0);
            aHk = __builtin_amdgcn_mfma_f32_16x16x32_bf16(avK, Wf[8704 + ((wv >> 1) * 4 + ks) * 64 + lane], aHk, 0, 0, 0);
        }
        __syncthreads();
#pragma unroll
        for (int nt = 0; nt < 4; ++nt) {
            int colc = (ng4 + nt) * 16 + col0;
            int vks = colc >> 5, vq = (colc >> 3) & 3, vj = colc & 7;
#pragma unroll
            for (int reg = 0; reg < 4; ++reg) {
                int row = Mtk * 16 + quad * 4 + reg;
                Ks[row * 132 + colc] = aK[nt][reg];
                int idx = (Mtk * 4 + vks) * 64 + vq * 16 + (quad * 4 + reg);
                Vfrag[idx * 8 + vj] = f2bf(aV[nt][reg]);
            }
        }
#pragma unroll
        for (int nt = 0; nt < 2; ++nt) {
            int colc = (wv * 2 + nt) * 16 + col0;
#pragma unroll
            for (int reg = 0; reg < 4; ++reg)
                Qs[(quad * 4 + reg) * 128 + colc] = aQ[nt][reg];
        }
        if (wv < 2) {
            int h = wv * 16 + col0;
#pragma unroll
            for (int reg = 0; reg < 4; ++reg)
                hqT[h * 18 + (quad * 4 + reg)] = f2bf(aHq[reg] + b1s[h]);
        }
        {
            int h = (wv >> 1) * 16 + col0;
#pragma unroll
            for (int reg = 0; reg < 4; ++reg)
                hks[(Mtk * 16 + quad * 4 + reg) * 34 + h] = f2bf(aHk[reg]);
        }
    }
    __syncthreads();

    {
        const int m = m3, n2 = n23;
        const float* krow = Ks + m * 132;
        const float* q0 = Qs + (n2 * 2) * 128;
        const float* q1 = Qs + (n2 * 2 + 1) * 128;
        float acc0 = 0.f, acc1 = 0.f;
        for (int j = 0; j < 128; j += 4) {
            float4 k4 = *(const float4*)(krow + j);
            float4 qa = *(const float4*)(q0 + j);
            float4 qb = *(const float4*)(q1 + j);
            acc0 = fmaf(qa.x, k4.x, fmaf(qa.y, k4.y, fmaf(qa.z, k4.z, fmaf(qa.w, k4.w, acc0))));
            acc1 = fmaf(qb.x, k4.x, fmaf(qb.y, k4.y, fmaf(qb.z, k4.z, fmaf(qb.w, k4.w, acc1))));
        }
        float pacc[2] = {0.f, 0.f};
        for (int h = 0; h < 32; ++h) {
            float4 we = W1e_s[h];
            float w2v = W2_s[h];
            float hkv = bf2f(hks[m * 34 + h]);
            float hq0 = bf2f(hqT[h * 18 + n2 * 2]);
            float hq1 = bf2f(hqT[h * 18 + n2 * 2 + 1]);
            float he0 = fmaf(e4[0].x, we.x, fmaf(e4[0].y, we.y, fmaf(e4[0].z, we.z, e4[0].w * we.w)));
            float he1 = fmaf(e4[1].x, we.x, fmaf(e4[1].y, we.y, fmaf(e4[1].z, we.z, e4[1].w * we.w)));
            pacc[0] = fmaf(fmaxf(hq0 + hkv + he0, 0.f), w2v, pacc[0]);
            pacc[1] = fmaf(fmaxf(hq1 + hkv + he1, 0.f), w2v, pacc[1]);
        }
        float cont[2] = {acc0, acc1};
#pragma unroll
        for (int r = 0; r < 2; ++r) {
            int nloc = n2 * 2 + r, ng = half * 16 + nloc;
            float pr = pr5[r][0]*Wf_s[0] + pr5[r][1]*Wf_s[1] + pr5[r][2]*Wf_s[2]
                     + pr5[r][3]*Wf_s[3] + pr5[r][4]*Wf_s[4];
            if (!(fabsf(pr) < 1e30f)) pr = 0.f;
            pr = fmaxf(pr, 0.f);
            float lg = cont[r] * 0.08838834764831845f
                     + pw * (pacc[r] + b2v) + rw_ * __logf(pr + 1e-6f);
            if (maskrow[ng] != 0.f || maskrow[m] != 0.f) lg = -1e9f;
            Lg[nloc * 33 + m] = lg;
        }
    }
    __syncthreads();

    if (tid < 16) {
        const int n = tid;
        float mx = -3.4e38f;
        for (int m2 = 0; m2 < 32; ++m2) mx = fmaxf(mx, Lg[n * 33 + m2]);
        float s = 0.f;
        for (int m2 = 0; m2 < 32; ++m2) {
            float e = __expf(Lg[n * 33 + m2] - mx);
            Lg[n * 33 + m2] = e; s += e;
        }
        float inv = 1.f / s;
        for (int m2 = 0; m2 < 32; ++m2) Lg[n * 33 + m2] *= inv;
    }
    __syncthreads();

    {
        const int d0 = (tid & 31) * 4, nl0 = (tid >> 5) * 2;
        const int vks = d0 >> 5, vq = (d0 >> 3) & 3, vj = d0 & 7;
        float sa[2][4] = {{0,0,0,0},{0,0,0,0}};
        for (int m = 0; m < 32; ++m) {
            int idx = ((m >> 4) * 4 + vks) * 64 + vq * 16 + (m & 15);
            const unsigned short* vp = Vfrag + idx * 8 + vj;
            float v0 = bf2f(vp[0]), v1 = bf2f(vp[1]), v2 = bf2f(vp[2]), v3 = bf2f(vp[3]);
            float a0 = Lg[nl0 * 33 + m], a1 = Lg[(nl0 + 1) * 33 + m];
            sa[0][0]=fmaf(a0,v0,sa[0][0]); sa[0][1]=fmaf(a0,v1,sa[0][1]);
            sa[0][2]=fmaf(a0,v2,sa[0][2]); sa[0][3]=fmaf(a0,v3,sa[0][3]);
            sa[1][0]=fmaf(a1,v0,sa[1][0]); sa[1][1]=fmaf(a1,v1,sa[1][1]);
            sa[1][2]=fmaf(a1,v2,sa[1][2]); sa[1][3]=fmaf(a1,v3,sa[1][3]);
        }
#pragma unroll
        for (int r = 0; r < 2; ++r) {
            int nloc = nl0 + r;
            unsigned short* sp = Sfrag + (vks * 64 + vq * 16 + nloc) * 8 + vj;
            sp[0] = f2bf(sa[r][0]); sp[1] = f2bf(sa[r][1]);
            sp[2] = f2bf(sa[r][2]); sp[3] = f2bf(sa[r][3]);
        }
    }
    __syncthreads();

    {
        f32x4 aT[2] = {{0.f,0.f,0.f,0.f},{0.f,0.f,0.f,0.f}};
#pragma unroll
        for (int ks = 0; ks < 4; ++ks) {
            bf16x8 av = *(const bf16x8*)(Sfrag + (ks * 64 + lane) * 8);
#pragma unroll
            for (int nt = 0; nt < 2; ++nt)
                aT[nt] = __builtin_amdgcn_mfma_f32_16x16x32_bf16(
                    av, Wf[6144 + ((wv * 2 + nt) * 4 + ks) * 64 + lane], aT[nt], 0, 0, 0);
        }
#pragma unroll
        for (int nt = 0; nt < 2; ++nt) {
            int colc = (wv * 2 + nt) * 16 + col0;
#pragma unroll
            for (int reg = 0; reg < 4; ++reg)
                ThOut[(quad * 4 + reg) * 128 + colc] = aT[nt][reg];
        }
    }
    __syncthreads();

    {
        const int d0 = (tid & 31) * 4, n2 = tid >> 5;
        float4 g4  = *(const float4*)(gma + d0);
        float4 be4 = *(const float4*)(bta + d0);
#pragma unroll
        for (int r = 0; r < 2; ++r) {
            int nloc = n2 * 2 + r, ng = half * 16 + nloc;
            const float* xr = x + ((size_t)((b_ * 32 + ng) * 64 + t_)) * 128 + d0;
            float4 z  = *(const float4*)(xr);
            float4 th = *(const float4*)(ThOut + nloc * 128 + d0);
            float y0 = th.x + z.x, y1 = th.y + z.y, y2 = th.z + z.z, y3 = th.w + z.w;
            float s  = (y0 + y1) + (y2 + y3);
            float s2 = (y0*y0 + y1*y1) + (y2*y2 + y3*y3);
#pragma unroll
            for (int off = 1; off < 32; off <<= 1) {
                s  += __shfl_xor(s,  off, 64);
                s2 += __shfl_xor(s2, off, 64);
            }
            float mu   = s * 0.0078125f;
            float var  = s2 * 0.0078125f - mu * mu;
            float rstd = rsqrtf(var + 1e-5f);
            float msk  = (maskrow[ng] != 0.f) ? 0.f : 1.f;
            float4 o;
            o.x = ((y0 - mu) * rstd * g4.x + be4.x) * msk;
            o.y = ((y1 - mu) * rstd * g4.y + be4.y) * msk;
            o.z = ((y2 - mu) * rstd * g4.z + be4.z) * msk;
            o.w = ((y3 - mu) * rstd * g4.w + be4.w) * msk;
            *(float4*)(out + ((size_t)((b_ * 32 + ng) * 64 + t_)) * 128 + d0) = o;
        }
    }
}

// ===========================================================================
extern "C" void kernel_launch(void* const* d_in, const int* in_sizes, int n_in,
                              void* d_out, int out_size, void* d_ws, size_t ws_size,
                              hipStream_t stream) {
    const float* x        = (const float*)d_in[0];
    const float* edge     = (const float*)d_in[1];
    const float* A_prior  = (const float*)d_in[2];
    const unsigned char* pad_mask = (const unsigned char*)d_in[3];
    const float* Wq       = (const float*)d_in[4];
    const float* Wk       = (const float*)d_in[5];
    const float* Wv       = (const float*)d_in[6];
    const float* Theta    = (const float*)d_in[7];
    const float* Wfuse    = (const float*)d_in[8];
    const float* W1       = (const float*)d_in[9];
    const float* b1       = (const float*)d_in[10];
    const float* W2       = (const float*)d_in[11];
    const float* b2       = (const float*)d_in[12];
    const float* gma      = (const float*)d_in[13];
    const float* bta      = (const float*)d_in[14];
    const float* physw    = (const float*)d_in[15];
    const float* priorw   = (const float*)d_in[16];
    float* out = (float*)d_out;

    unsigned short* Wfrag = (unsigned short*)d_ws;   // 147456 B

    // workspace layout (fast path):
    //   [0,147456)            Wfrag
    //   +8388608              Qws   fp32 [16384][128]
    //   +8388608              Kws   fp32 [16384][128]
    //   +4194304              Vws   bf16 [16384][128]
    //   +1048576              hqws  bf16 [16384][32]
    //   +1048576              hkws  bf16 [16384][32]
    const size_t NEED = 147456ull + 8388608ull * 2 + 4194304ull + 1048576ull * 2; // 23216128

    if (ws_size >= NEED) {
        float* Qws = (float*)((char*)d_ws + 147456);
        float* Kws = (float*)((char*)d_ws + 147456 + 8388608ull);
        unsigned short* Vws  = (unsigned short*)((char*)d_ws + 147456 + 16777216ull);
        unsigned short* hqws = (unsigned short*)((char*)d_ws + 147456 + 16777216ull + 4194304ull);
        unsigned short* hkws = hqws + (size_t)16384 * 32;

        k0_prep<<<dim3(64), dim3(256), 0, stream>>>(Wq, Wk, Wv, Theta, W1, Wfrag);
        k1_proj<<<dim3(512), dim3(256), 0, stream>>>(x, Wfrag, b1, Qws, Kws, Vws, hqws, hkws);
        k2_attn<<<dim3(512), dim3(256), 0, stream>>>(
            x, edge, A_prior, pad_mask, Wfrag, Wfuse, W1, W2, b2,
            gma, bta, physw, priorw, Qws, Kws, Vws, hqws, hkws, out);
    } else {
        // R9 fallback
        k0a_pack_w<<<dim3(32), dim3(256), 0, stream>>>(Wq, Wk, Wv, Theta, Wfrag);
        k0b_compose<<<dim3(8), dim3(256), 0, stream>>>(Wq, Wk, W1, Wfrag);
        gnn_fused<<<dim3(1024), dim3(256), 0, stream>>>(
            x, edge, A_prior, pad_mask, Wfrag, Wfuse,
            W1, b1, W2, b2, gma, bta, physw, priorw, out);
    }
}